// Round 4
// baseline (378.065 us; speedup 1.0000x reference)
//
#include <hip/hip_runtime.h>
#include <hip/hip_bf16.h>
#include <stdint.h>

#define BATCH  16384
#define GAMMA  0.01f

using f32x4  = __attribute__((ext_vector_type(4))) float;
using bf16x8 = __attribute__((ext_vector_type(8))) __bf16;

#define MFMA16(a, b, c) __builtin_amdgcn_mfma_f32_16x16x32_bf16((a), (b), (c), 0, 0, 0)
#define BAR() asm volatile("s_barrier" ::: "memory")

// ---------- helpers ----------
__device__ __forceinline__ unsigned short f2bf(float f) {
  unsigned int u = __float_as_uint(f);
  unsigned int r = (u + 0x7fffu + ((u >> 16) & 1u)) >> 16;  // RNE
  return (unsigned short)r;
}
__device__ __forceinline__ float bf2f(unsigned short u) {
  return __uint_as_float(((unsigned int)u) << 16);
}
__device__ __forceinline__ float sigmoidf_(float x) {
  return 1.0f / (1.0f + __expf(-x));
}
__device__ __forceinline__ float tanhf_(float x) {
  float e = __expf(2.0f * x);
  return (e - 1.0f) / (e + 1.0f);
}
__device__ __forceinline__ void gload_lds16(const void* gsrc, void* ldst) {
  __builtin_amdgcn_global_load_lds(
      (const __attribute__((address_space(1))) void*)gsrc,
      (__attribute__((address_space(3))) void*)ldst, 16, 0, 0);
}

// ---------- 256x256 GEMM: C = X[M][K] @ W[N][K]^T (bf16 in, epilogue varies) ----
// K-loop schedule: EXACTLY the R2-verified one (948 TF on GEMM1):
//   P1: STAGE_A(cn,1,k1)  P2: STAGE_B(cn,0,k1)  P3: STAGE_B(cn,1,k1)
//   P4: STAGE_A(c,0,k2) + counted vmcnt(2)  [never 0 until tail]
// (R3's variant -- staging T+2 B-halves into the in-use buffer at P3/P4 --
//  measured 565 TF vs this schedule's 948 TF. Do not "improve" this again
//  without a within-round A/B.)
// EPI: 0 = plain bf16 C store; 1 = AGRU gate epilogue (Zs | Hr);
//      3 = final combine (out = h + eps*Zs*tanh(Vpre+bh+acc)).
template <int EPI>
__global__ __launch_bounds__(512, 2) void gemm256(
    const unsigned short* __restrict__ X, const unsigned short* __restrict__ W,
    unsigned short* __restrict__ C, unsigned short* __restrict__ C2,
    int lda, int K, int N,
    const float* __restrict__ p0, const float* __restrict__ p1,
    const float* __restrict__ p2,
    const unsigned short* __restrict__ q0, const unsigned short* __restrict__ q1,
    float* __restrict__ fout, const float* __restrict__ epsp) {
  __shared__ unsigned short As[2 * 16384];
  __shared__ unsigned short Bs[2 * 16384];

  // XCD-aware bijective swizzle (all grids here are multiples of 8)
  const int qq  = gridDim.x >> 3;
  const int swz = (blockIdx.x & 7) * qq + (blockIdx.x >> 3);
  const int tiles_n = N >> 8;
  const int brow = swz / tiles_n;
  const int bcol = swz % tiles_n;

  const int t    = threadIdx.x;
  const int lane = t & 63;
  const int wave = t >> 6;
  const int wm   = wave >> 2;     // 0..1
  const int wn   = wave & 3;      // 0..3
  const int lr   = lane & 15;
  const int kq8  = (lane >> 4) * 8;
  const int sx   = (lr & 7) << 3;           // read-side swizzle (shorts)
  const int koff0 = kq8 ^ sx;
  const int koff1 = (32 + kq8) ^ sx;
  const int aBase = (wm * 128 + lr) * 64;
  const int bBase = (wn * 64 + lr) * 64;

  // staging: thread t covers row (t>>3), 16B granule (t&7), pre-swizzled source
  const int srow = t >> 3;                  // 0..63
  const int sg   = (t & 7) ^ (srow & 7);
  const unsigned short* aSrc = X + (size_t)(brow * 256 + srow) * lda + sg * 8;
  const unsigned short* bSrc = W + (size_t)(bcol * 256 + srow) * K + sg * 8;
  const int wofs = wave * 512;

  auto STAGE_A = [&](int buf, int h, int k0) {
    gload_lds16(aSrc + (size_t)(h * 128) * lda + k0,
                As + buf * 16384 + (h * 128) * 64 + wofs);
    gload_lds16(aSrc + (size_t)(h * 128 + 64) * lda + k0,
                As + buf * 16384 + (h * 128 + 64) * 64 + wofs);
  };
  auto STAGE_B = [&](int buf, int h, int k0) {
    gload_lds16(bSrc + (size_t)(h * 128) * K + k0,
                Bs + buf * 16384 + (h * 128) * 64 + wofs);
    gload_lds16(bSrc + (size_t)(h * 128 + 64) * K + k0,
                Bs + buf * 16384 + (h * 128 + 64) * 64 + wofs);
  };

  f32x4 acc[8][4] = {};
  bf16x8 aR[4][2], bR[4][2];

  const int nt = K >> 6;  // nt >= 2 for all our shapes

  // ---- prologue: tile 0 fully + tile 1 A-half0; leave A0(1) in flight
  STAGE_A(0, 0, 0); STAGE_A(0, 1, 0); STAGE_B(0, 0, 0); STAGE_B(0, 1, 0);
  STAGE_A(1, 0, 64);
  asm volatile("s_waitcnt vmcnt(2)" ::: "memory");
  BAR();

  for (int T = 0; T < nt; ++T) {
    const int c  = T & 1;
    const int cn = c ^ 1;
    const int k1 = (T + 1) << 6;
    const int k2 = (T + 2) << 6;
    const unsigned short* Ac = As + c * 16384;
    const unsigned short* Bc = Bs + c * 16384;

    // ---- P1: read A i0-3 + B j0-1; stage A1(T+1)->cn; compute Q0
#pragma unroll
    for (int i = 0; i < 4; ++i) {
      aR[i][0] = *(const bf16x8*)(Ac + aBase + i * 1024 + koff0);
      aR[i][1] = *(const bf16x8*)(Ac + aBase + i * 1024 + koff1);
    }
#pragma unroll
    for (int j = 0; j < 2; ++j) {
      bR[j][0] = *(const bf16x8*)(Bc + bBase + j * 1024 + koff0);
      bR[j][1] = *(const bf16x8*)(Bc + bBase + j * 1024 + koff1);
    }
    if (T + 1 < nt) STAGE_A(cn, 1, k1);
    BAR();
    __builtin_amdgcn_s_setprio(1);
#pragma unroll
    for (int i = 0; i < 4; ++i)
#pragma unroll
      for (int j = 0; j < 2; ++j) {
        acc[i][j] = MFMA16(aR[i][0], bR[j][0], acc[i][j]);
        acc[i][j] = MFMA16(aR[i][1], bR[j][1], acc[i][j]);
      }
    __builtin_amdgcn_s_setprio(0);
    BAR();

    // ---- P2: read B j2-3; stage B0(T+1)->cn; compute Q1
#pragma unroll
    for (int j = 2; j < 4; ++j) {
      bR[j][0] = *(const bf16x8*)(Bc + bBase + j * 1024 + koff0);
      bR[j][1] = *(const bf16x8*)(Bc + bBase + j * 1024 + koff1);
    }
    if (T + 1 < nt) STAGE_B(cn, 0, k1);
    BAR();
    __builtin_amdgcn_s_setprio(1);
#pragma unroll
    for (int i = 0; i < 4; ++i)
#pragma unroll
      for (int j = 2; j < 4; ++j) {
        acc[i][j] = MFMA16(aR[i][0], bR[j][0], acc[i][j]);
        acc[i][j] = MFMA16(aR[i][1], bR[j][1], acc[i][j]);
      }
    __builtin_amdgcn_s_setprio(0);
    BAR();

    // ---- P3: read A i4-7; stage B1(T+1)->cn; compute Q2
#pragma unroll
    for (int i = 0; i < 4; ++i) {
      aR[i][0] = *(const bf16x8*)(Ac + aBase + (i + 4) * 1024 + koff0);
      aR[i][1] = *(const bf16x8*)(Ac + aBase + (i + 4) * 1024 + koff1);
    }
    if (T + 1 < nt) STAGE_B(cn, 1, k1);
    BAR();
    __builtin_amdgcn_s_setprio(1);
#pragma unroll
    for (int i = 0; i < 4; ++i)
#pragma unroll
      for (int j = 0; j < 2; ++j) {
        acc[i + 4][j] = MFMA16(aR[i][0], bR[j][0], acc[i + 4][j]);
        acc[i + 4][j] = MFMA16(aR[i][1], bR[j][1], acc[i + 4][j]);
      }
    __builtin_amdgcn_s_setprio(0);
    BAR();

    // ---- P4: stage A0(T+2)->c (freed); compute Q3; counted vmcnt(2)
    if (T + 2 < nt) STAGE_A(c, 0, k2);
    __builtin_amdgcn_s_setprio(1);
#pragma unroll
    for (int i = 0; i < 4; ++i)
#pragma unroll
      for (int j = 2; j < 4; ++j) {
        acc[i + 4][j] = MFMA16(aR[i][0], bR[j][0], acc[i + 4][j]);
        acc[i + 4][j] = MFMA16(aR[i][1], bR[j][1], acc[i + 4][j]);
      }
    __builtin_amdgcn_s_setprio(0);
    if (T + 2 < nt) { asm volatile("s_waitcnt vmcnt(2)" ::: "memory"); }
    else            { asm volatile("s_waitcnt vmcnt(0)" ::: "memory"); }
    BAR();
  }

  // ---- epilogue: C/D layout col=lane&15, row=(lane>>4)*4+reg
  const int rbase = brow * 256 + wm * 128 + (lane >> 4) * 4;
  const int cbase = bcol * 256 + wn * 64 + lr;

  if constexpr (EPI == 1) {
    // z-cols (<1024): Zs=sigmoid(acc+bz) -> C ; r-cols: Hr=sigmoid(acc+br)*h -> C2
    const bool zh = (bcol * 256) < 1024;
#pragma unroll
    for (int i = 0; i < 8; ++i)
#pragma unroll
      for (int j = 0; j < 4; ++j)
#pragma unroll
        for (int q = 0; q < 4; ++q) {
          const int row = rbase + i * 16 + q;
          const int col = cbase + j * 16;
          const float v = acc[i][j][q];
          if (zh) {
            C[(size_t)row * 1024 + col] = f2bf(sigmoidf_(v + p0[col]));
          } else {
            const int c2 = col - 1024;
            const size_t e = (size_t)row * 1024 + c2;
            C2[e] = f2bf(sigmoidf_(v + p1[c2]) * p2[e]);
          }
        }
  } else if constexpr (EPI == 3) {
    // out = h + eps * Zs * tanh(Vpre + bh + acc)
    const float eps = epsp[0];
#pragma unroll
    for (int i = 0; i < 8; ++i)
#pragma unroll
      for (int j = 0; j < 4; ++j)
#pragma unroll
        for (int q = 0; q < 4; ++q) {
          const int row = rbase + i * 16 + q;
          const int col = cbase + j * 16;
          const size_t e = (size_t)row * 1024 + col;
          const float tv = tanhf_(bf2f(q1[e]) + p0[col] + acc[i][j][q]);
          fout[e] = p2[e] + eps * bf2f(q0[e]) * tv;
        }
  } else {
#pragma unroll
    for (int i = 0; i < 8; ++i)
#pragma unroll
      for (int j = 0; j < 4; ++j)
#pragma unroll
        for (int q = 0; q < 4; ++q)
          C[(size_t)(rbase + i * 16 + q) * N + cbase + j * 16] = f2bf(acc[i][j][q]);
  }
}

// ---------- prep kernels ----------
__global__ void prep_x_kernel(const float* __restrict__ x, const float* __restrict__ h,
                              unsigned short* __restrict__ Xcat) {
  const int total4 = BATCH * 2048 / 4;
  for (int i = blockIdx.x * blockDim.x + threadIdx.x; i < total4; i += gridDim.x * blockDim.x) {
    const int e = i * 4;
    const int m = e >> 11;
    const int c = e & 2047;
    float4 v = (c < 1024) ? *(const float4*)(x + (size_t)m * 1024 + c)
                          : *(const float4*)(h + (size_t)m * 1024 + (c - 1024));
    ushort4 o;
    o.x = f2bf(v.x); o.y = f2bf(v.y); o.z = f2bf(v.z); o.w = f2bf(v.w);
    *(ushort4*)(Xcat + e) = o;
  }
}

__global__ void prep_wcat_kernel(const float* __restrict__ Wz, const float* __restrict__ Uz,
                                 const float* __restrict__ Wr, const float* __restrict__ Ur,
                                 unsigned short* __restrict__ Wcat) {
  const int total4 = 2048 * 2048 / 4;
  for (int i = blockIdx.x * blockDim.x + threadIdx.x; i < total4; i += gridDim.x * blockDim.x) {
    const int e = i * 4;
    const int n = e >> 11;
    const int c = e & 2047;
    const float* src;
    if (n < 1024) src = (c < 1024) ? (Wz + (size_t)n * 1024 + c) : (Uz + (size_t)n * 1024 + c - 1024);
    else          src = (c < 1024) ? (Wr + (size_t)(n - 1024) * 1024 + c) : (Ur + (size_t)(n - 1024) * 1024 + c - 1024);
    float4 v = *(const float4*)src;
    ushort4 o;
    o.x = f2bf(v.x); o.y = f2bf(v.y); o.z = f2bf(v.z); o.w = f2bf(v.w);
    *(ushort4*)(Wcat + e) = o;
  }
}

__global__ void cast_f2b_kernel(const float* __restrict__ src, unsigned short* __restrict__ dst,
                                int total4) {
  for (int i = blockIdx.x * blockDim.x + threadIdx.x; i < total4; i += gridDim.x * blockDim.x) {
    const int e = i * 4;
    float4 v = *(const float4*)(src + e);
    ushort4 o;
    o.x = f2bf(v.x); o.y = f2bf(v.y); o.z = f2bf(v.z); o.w = f2bf(v.w);
    *(ushort4*)(dst + e) = o;
  }
}

__global__ void prep_A_kernel(const float* __restrict__ Wh, unsigned short* __restrict__ Abf) {
  const int total4 = 1024 * 1024 / 4;
  for (int i = blockIdx.x * blockDim.x + threadIdx.x; i < total4; i += gridDim.x * blockDim.x) {
    const int e = i * 4;
    const int r = e >> 10;
    const int c = e & 1023;
    float4 v = *(const float4*)(Wh + (size_t)r * 1024 + c);
    float t0 = Wh[(size_t)(c + 0) * 1024 + r];
    float t1 = Wh[(size_t)(c + 1) * 1024 + r];
    float t2 = Wh[(size_t)(c + 2) * 1024 + r];
    float t3 = Wh[(size_t)(c + 3) * 1024 + r];
    ushort4 o;
    o.x = f2bf(v.x - t0 - ((r == c + 0) ? GAMMA : 0.0f));
    o.y = f2bf(v.y - t1 - ((r == c + 1) ? GAMMA : 0.0f));
    o.z = f2bf(v.z - t2 - ((r == c + 2) ? GAMMA : 0.0f));
    o.w = f2bf(v.w - t3 - ((r == c + 3) ? GAMMA : 0.0f));
    *(ushort4*)(Abf + e) = o;
  }
}

// ---------- launch ----------
extern "C" void kernel_launch(void* const* d_in, const int* in_sizes, int n_in,
                              void* d_out, int out_size, void* d_ws, size_t ws_size,
                              hipStream_t stream) {
  const float* x   = (const float*)d_in[0];
  const float* h   = (const float*)d_in[1];
  const float* Wz  = (const float*)d_in[2];
  const float* bz  = (const float*)d_in[3];
  const float* Uz  = (const float*)d_in[4];
  const float* Wr  = (const float*)d_in[5];
  const float* br  = (const float*)d_in[6];
  const float* Ur  = (const float*)d_in[7];
  const float* Vh  = (const float*)d_in[8];
  const float* bh  = (const float*)d_in[9];
  const float* Wh  = (const float*)d_in[10];
  const float* eps = (const float*)d_in[11];
  float* out = (float*)d_out;

  char* ws = (char*)d_ws;
  size_t off = 0;
  unsigned short* Xcat = (unsigned short*)(ws + off); off += (size_t)BATCH * 2048 * 2;
  unsigned short* Wcat = (unsigned short*)(ws + off); off += (size_t)2048 * 2048 * 2;
  unsigned short* Vhb  = (unsigned short*)(ws + off); off += (size_t)1024 * 1024 * 2;
  unsigned short* Abf  = (unsigned short*)(ws + off); off += (size_t)1024 * 1024 * 2;
  unsigned short* Zs   = (unsigned short*)(ws + off); off += (size_t)BATCH * 1024 * 2;
  unsigned short* Hr   = (unsigned short*)(ws + off); off += (size_t)BATCH * 1024 * 2;
  unsigned short* Vpre = (unsigned short*)(ws + off); off += (size_t)BATCH * 1024 * 2;

  dim3 blk(256);
  prep_x_kernel<<<2048, blk, 0, stream>>>(x, h, Xcat);
  prep_wcat_kernel<<<1024, blk, 0, stream>>>(Wz, Uz, Wr, Ur, Wcat);
  cast_f2b_kernel<<<256, blk, 0, stream>>>(Vh, Vhb, 1024 * 1024 / 4);
  prep_A_kernel<<<256, blk, 0, stream>>>(Wh, Abf);

  dim3 gblk(512);
  // GEMM1 (fused gates): [z_pre|r_pre] = Xcat @ Wcat^T -> Zs, Hr
  gemm256<1><<<(BATCH / 256) * (2048 / 256), gblk, 0, stream>>>(
      Xcat, Wcat, Zs, Hr, 2048, 2048, 2048, bz, br, h, nullptr, nullptr, nullptr, nullptr);
  // GEMM2 (plain): Vpre = x @ Vh^T
  gemm256<0><<<(BATCH / 256) * (1024 / 256), gblk, 0, stream>>>(
      Xcat, Vhb, Vpre, nullptr, 2048, 1024, 1024,
      nullptr, nullptr, nullptr, nullptr, nullptr, nullptr, nullptr);
  // GEMM3 (fused combine): out = h + eps*Zs*tanh(Vpre + bh + Hr@A^T)
  gemm256<3><<<(BATCH / 256) * (1024 / 256), gblk, 0, stream>>>(
      Hr, Abf, nullptr, nullptr, 1024, 1024, 1024,
      bh, nullptr, h, Zs, Vpre, out, eps);
}

// Round 5
// 310.521 us; speedup vs baseline: 1.2175x; 1.2175x over previous
//
#include <hip/hip_runtime.h>
#include <hip/hip_bf16.h>
#include <stdint.h>

#define BATCH  16384
#define GAMMA  0.01f

using f32x4  = __attribute__((ext_vector_type(4))) float;
using bf16x8 = __attribute__((ext_vector_type(8))) __bf16;

#define MFMA16(a, b, c) __builtin_amdgcn_mfma_f32_16x16x32_bf16((a), (b), (c), 0, 0, 0)
#define BAR() asm volatile("s_barrier" ::: "memory")

// ---------- helpers ----------
__device__ __forceinline__ unsigned short f2bf(float f) {
  unsigned int u = __float_as_uint(f);
  unsigned int r = (u + 0x7fffu + ((u >> 16) & 1u)) >> 16;  // RNE
  return (unsigned short)r;
}
__device__ __forceinline__ float bf2f(unsigned short u) {
  return __uint_as_float(((unsigned int)u) << 16);
}
__device__ __forceinline__ float sigmoidf_(float x) {
  return 1.0f / (1.0f + __expf(-x));
}
__device__ __forceinline__ float tanhf_(float x) {
  float e = __expf(2.0f * x);
  return (e - 1.0f) / (e + 1.0f);
}
__device__ __forceinline__ void gload_lds16(const void* gsrc, void* ldst) {
  __builtin_amdgcn_global_load_lds(
      (const __attribute__((address_space(1))) void*)gsrc,
      (__attribute__((address_space(3))) void*)ldst, 16, 0, 0);
}

// =====================================================================
// Shared K-loop body (R2-verified schedule, 948 TF on GEMM1).
//   P1: STAGE_A(cn,1,k1)  P2: STAGE_B(cn,0,k1)  P3: STAGE_B(cn,1,k1)
//   P4: STAGE_A(c,0,k2) + counted vmcnt(2)
// Used via macro so each kernel is an independent top-level function
// (no shared template instantiation context -- R3/R4 lesson).
// =====================================================================
#define GEMM_PREAMBLE_AND_KLOOP(X_, W_, lda_, K_, N_)                          \
  __shared__ unsigned short As[2 * 16384];                                     \
  __shared__ unsigned short Bs[2 * 16384];                                     \
  const int qq  = gridDim.x >> 3;                                              \
  const int swz = (blockIdx.x & 7) * qq + (blockIdx.x >> 3);                   \
  const int tiles_n = (N_) >> 8;                                               \
  const int brow = swz / tiles_n;                                              \
  const int bcol = swz % tiles_n;                                              \
  const int t    = threadIdx.x;                                                \
  const int lane = t & 63;                                                     \
  const int wave = t >> 6;                                                     \
  const int wm   = wave >> 2;                                                  \
  const int wn   = wave & 3;                                                   \
  const int lr   = lane & 15;                                                  \
  const int kq8  = (lane >> 4) * 8;                                            \
  const int sx   = (lr & 7) << 3;                                              \
  const int koff0 = kq8 ^ sx;                                                  \
  const int koff1 = (32 + kq8) ^ sx;                                           \
  const int aBase = (wm * 128 + lr) * 64;                                      \
  const int bBase = (wn * 64 + lr) * 64;                                       \
  const int srow = t >> 3;                                                     \
  const int sg   = (t & 7) ^ (srow & 7);                                       \
  const unsigned short* aSrc = (X_) + (size_t)(brow * 256 + srow) * (lda_) + sg * 8; \
  const unsigned short* bSrc = (W_) + (size_t)(bcol * 256 + srow) * (K_) + sg * 8;   \
  const int wofs = wave * 512;                                                 \
  auto STAGE_A = [&](int buf, int h, int k0) {                                 \
    gload_lds16(aSrc + (size_t)(h * 128) * (lda_) + k0,                        \
                As + buf * 16384 + (h * 128) * 64 + wofs);                     \
    gload_lds16(aSrc + (size_t)(h * 128 + 64) * (lda_) + k0,                   \
                As + buf * 16384 + (h * 128 + 64) * 64 + wofs);                \
  };                                                                           \
  auto STAGE_B = [&](int buf, int h, int k0) {                                 \
    gload_lds16(bSrc + (size_t)(h * 128) * (K_) + k0,                          \
                Bs + buf * 16384 + (h * 128) * 64 + wofs);                     \
    gload_lds16(bSrc + (size_t)(h * 128 + 64) * (K_) + k0,                     \
                Bs + buf * 16384 + (h * 128 + 64) * 64 + wofs);                \
  };                                                                           \
  f32x4 acc[8][4] = {};                                                        \
  bf16x8 aR[4][2], bR[4][2];                                                   \
  const int nt = (K_) >> 6;                                                    \
  STAGE_A(0, 0, 0); STAGE_A(0, 1, 0); STAGE_B(0, 0, 0); STAGE_B(0, 1, 0);      \
  STAGE_A(1, 0, 64);                                                           \
  asm volatile("s_waitcnt vmcnt(2)" ::: "memory");                             \
  BAR();                                                                       \
  for (int T = 0; T < nt; ++T) {                                               \
    const int c  = T & 1;                                                      \
    const int cn = c ^ 1;                                                      \
    const int k1 = (T + 1) << 6;                                               \
    const int k2 = (T + 2) << 6;                                               \
    const unsigned short* Ac = As + c * 16384;                                 \
    const unsigned short* Bc = Bs + c * 16384;                                 \
    _Pragma("unroll")                                                          \
    for (int i = 0; i < 4; ++i) {                                              \
      aR[i][0] = *(const bf16x8*)(Ac + aBase + i * 1024 + koff0);              \
      aR[i][1] = *(const bf16x8*)(Ac + aBase + i * 1024 + koff1);              \
    }                                                                          \
    _Pragma("unroll")                                                          \
    for (int j = 0; j < 2; ++j) {                                              \
      bR[j][0] = *(const bf16x8*)(Bc + bBase + j * 1024 + koff0);              \
      bR[j][1] = *(const bf16x8*)(Bc + bBase + j * 1024 + koff1);              \
    }                                                                          \
    if (T + 1 < nt) STAGE_A(cn, 1, k1);                                        \
    BAR();                                                                     \
    __builtin_amdgcn_s_setprio(1);                                             \
    _Pragma("unroll")                                                          \
    for (int i = 0; i < 4; ++i)                                                \
      _Pragma("unroll")                                                        \
      for (int j = 0; j < 2; ++j) {                                            \
        acc[i][j] = MFMA16(aR[i][0], bR[j][0], acc[i][j]);                     \
        acc[i][j] = MFMA16(aR[i][1], bR[j][1], acc[i][j]);                     \
      }                                                                        \
    __builtin_amdgcn_s_setprio(0);                                             \
    BAR();                                                                     \
    _Pragma("unroll")                                                          \
    for (int j = 2; j < 4; ++j) {                                              \
      bR[j][0] = *(const bf16x8*)(Bc + bBase + j * 1024 + koff0);              \
      bR[j][1] = *(const bf16x8*)(Bc + bBase + j * 1024 + koff1);              \
    }                                                                          \
    if (T + 1 < nt) STAGE_B(cn, 0, k1);                                        \
    BAR();                                                                     \
    __builtin_amdgcn_s_setprio(1);                                             \
    _Pragma("unroll")                                                          \
    for (int i = 0; i < 4; ++i)                                                \
      _Pragma("unroll")                                                        \
      for (int j = 2; j < 4; ++j) {                                            \
        acc[i][j] = MFMA16(aR[i][0], bR[j][0], acc[i][j]);                     \
        acc[i][j] = MFMA16(aR[i][1], bR[j][1], acc[i][j]);                     \
      }                                                                        \
    __builtin_amdgcn_s_setprio(0);                                             \
    BAR();                                                                     \
    _Pragma("unroll")                                                          \
    for (int i = 0; i < 4; ++i) {                                              \
      aR[i][0] = *(const bf16x8*)(Ac + aBase + (i + 4) * 1024 + koff0);        \
      aR[i][1] = *(const bf16x8*)(Ac + aBase + (i + 4) * 1024 + koff1);        \
    }                                                                          \
    if (T + 1 < nt) STAGE_B(cn, 1, k1);                                        \
    BAR();                                                                     \
    __builtin_amdgcn_s_setprio(1);                                             \
    _Pragma("unroll")                                                          \
    for (int i = 0; i < 4; ++i)                                                \
      _Pragma("unroll")                                                        \
      for (int j = 0; j < 2; ++j) {                                            \
        acc[i + 4][j] = MFMA16(aR[i][0], bR[j][0], acc[i + 4][j]);             \
        acc[i + 4][j] = MFMA16(aR[i][1], bR[j][1], acc[i + 4][j]);             \
      }                                                                        \
    __builtin_amdgcn_s_setprio(0);                                             \
    BAR();                                                                     \
    if (T + 2 < nt) STAGE_A(c, 0, k2);                                         \
    __builtin_amdgcn_s_setprio(1);                                             \
    _Pragma("unroll")                                                          \
    for (int i = 0; i < 4; ++i)                                                \
      _Pragma("unroll")                                                        \
      for (int j = 2; j < 4; ++j) {                                            \
        acc[i + 4][j] = MFMA16(aR[i][0], bR[j][0], acc[i + 4][j]);             \
        acc[i + 4][j] = MFMA16(aR[i][1], bR[j][1], acc[i + 4][j]);             \
      }                                                                        \
    __builtin_amdgcn_s_setprio(0);                                             \
    if (T + 2 < nt) { asm volatile("s_waitcnt vmcnt(2)" ::: "memory"); }       \
    else            { asm volatile("s_waitcnt vmcnt(0)" ::: "memory"); }       \
    BAR();                                                                     \
  }                                                                            \
  const int rbase = brow * 256 + wm * 128 + (lane >> 4) * 4;                   \
  const int cbase = bcol * 256 + wn * 64 + lr;

// ---------- GEMM1: Zs = sigmoid(Xcat @ Wcat^T + bias), stride-2048 store ----
// Minimal delta vs the R2-verified plain kernel: same single-output store
// pattern, block-uniform bias side, sigmoid in-register. No branches/h-loads.
__global__ __launch_bounds__(512, 2) void gemm_sig(
    const unsigned short* __restrict__ X, const unsigned short* __restrict__ W,
    unsigned short* __restrict__ C, int lda, int K, int N,
    const float* __restrict__ bz, const float* __restrict__ br) {
  GEMM_PREAMBLE_AND_KLOOP(X, W, lda, K, N)
  const float* bias = (bcol * 256 < 1024) ? bz : (br - 1024);  // bias[col] valid
#pragma unroll
  for (int i = 0; i < 8; ++i)
#pragma unroll
    for (int j = 0; j < 4; ++j)
#pragma unroll
      for (int q = 0; q < 4; ++q) {
        const int col = cbase + j * 16;
        C[(size_t)(rbase + i * 16 + q) * N + col] =
            f2bf(sigmoidf_(acc[i][j][q] + bias[col]));
      }
}

// ---------- GEMM2: plain bf16 store (byte-equivalent to R2 kernel) ----------
__global__ __launch_bounds__(512, 2) void gemm_plain(
    const unsigned short* __restrict__ X, const unsigned short* __restrict__ W,
    unsigned short* __restrict__ C, int lda, int K, int N) {
  GEMM_PREAMBLE_AND_KLOOP(X, W, lda, K, N)
#pragma unroll
  for (int i = 0; i < 8; ++i)
#pragma unroll
    for (int j = 0; j < 4; ++j)
#pragma unroll
      for (int q = 0; q < 4; ++q)
        C[(size_t)(rbase + i * 16 + q) * N + cbase + j * 16] = f2bf(acc[i][j][q]);
}

// ---------- GEMM3: acc = Hr@A^T; out = h + eps*Zs*tanh(Vpre + bh + acc) -----
// Same shape as GEMM2 (N=K=1024) -> within-round A/B of epilogue weight.
__global__ __launch_bounds__(512, 2) void gemm_combine(
    const unsigned short* __restrict__ X, const unsigned short* __restrict__ W,
    int lda, int K, int N,
    const unsigned short* __restrict__ Zs, const unsigned short* __restrict__ Vpre,
    const float* __restrict__ bh, const float* __restrict__ h,
    const float* __restrict__ epsp, float* __restrict__ fout) {
  GEMM_PREAMBLE_AND_KLOOP(X, W, lda, K, N)
  const float eps = epsp[0];
#pragma unroll
  for (int i = 0; i < 8; ++i)
#pragma unroll
    for (int j = 0; j < 4; ++j)
#pragma unroll
      for (int q = 0; q < 4; ++q) {
        const int row = rbase + i * 16 + q;
        const int col = cbase + j * 16;
        const size_t e = (size_t)row * 1024 + col;
        const float tv = tanhf_(bf2f(Vpre[e]) + bh[col] + acc[i][j][q]);
        fout[e] = h[e] + eps * bf2f(Zs[(size_t)row * 2048 + col]) * tv;
      }
}

// ---------- prep kernels ----------
__global__ void prep_x_kernel(const float* __restrict__ x, const float* __restrict__ h,
                              unsigned short* __restrict__ Xcat) {
  const int total4 = BATCH * 2048 / 4;
  for (int i = blockIdx.x * blockDim.x + threadIdx.x; i < total4; i += gridDim.x * blockDim.x) {
    const int e = i * 4;
    const int m = e >> 11;
    const int c = e & 2047;
    float4 v = (c < 1024) ? *(const float4*)(x + (size_t)m * 1024 + c)
                          : *(const float4*)(h + (size_t)m * 1024 + (c - 1024));
    ushort4 o;
    o.x = f2bf(v.x); o.y = f2bf(v.y); o.z = f2bf(v.z); o.w = f2bf(v.w);
    *(ushort4*)(Xcat + e) = o;
  }
}

__global__ void prep_wcat_kernel(const float* __restrict__ Wz, const float* __restrict__ Uz,
                                 const float* __restrict__ Wr, const float* __restrict__ Ur,
                                 unsigned short* __restrict__ Wcat) {
  const int total4 = 2048 * 2048 / 4;
  for (int i = blockIdx.x * blockDim.x + threadIdx.x; i < total4; i += gridDim.x * blockDim.x) {
    const int e = i * 4;
    const int n = e >> 11;
    const int c = e & 2047;
    const float* src;
    if (n < 1024) src = (c < 1024) ? (Wz + (size_t)n * 1024 + c) : (Uz + (size_t)n * 1024 + c - 1024);
    else          src = (c < 1024) ? (Wr + (size_t)(n - 1024) * 1024 + c) : (Ur + (size_t)(n - 1024) * 1024 + c - 1024);
    float4 v = *(const float4*)src;
    ushort4 o;
    o.x = f2bf(v.x); o.y = f2bf(v.y); o.z = f2bf(v.z); o.w = f2bf(v.w);
    *(ushort4*)(Wcat + e) = o;
  }
}

__global__ void cast_f2b_kernel(const float* __restrict__ src, unsigned short* __restrict__ dst,
                                int total4) {
  for (int i = blockIdx.x * blockDim.x + threadIdx.x; i < total4; i += gridDim.x * blockDim.x) {
    const int e = i * 4;
    float4 v = *(const float4*)(src + e);
    ushort4 o;
    o.x = f2bf(v.x); o.y = f2bf(v.y); o.z = f2bf(v.z); o.w = f2bf(v.w);
    *(ushort4*)(dst + e) = o;
  }
}

__global__ void prep_A_kernel(const float* __restrict__ Wh, unsigned short* __restrict__ Abf) {
  const int total4 = 1024 * 1024 / 4;
  for (int i = blockIdx.x * blockDim.x + threadIdx.x; i < total4; i += gridDim.x * blockDim.x) {
    const int e = i * 4;
    const int r = e >> 10;
    const int c = e & 1023;
    float4 v = *(const float4*)(Wh + (size_t)r * 1024 + c);
    float t0 = Wh[(size_t)(c + 0) * 1024 + r];
    float t1 = Wh[(size_t)(c + 1) * 1024 + r];
    float t2 = Wh[(size_t)(c + 2) * 1024 + r];
    float t3 = Wh[(size_t)(c + 3) * 1024 + r];
    ushort4 o;
    o.x = f2bf(v.x - t0 - ((r == c + 0) ? GAMMA : 0.0f));
    o.y = f2bf(v.y - t1 - ((r == c + 1) ? GAMMA : 0.0f));
    o.z = f2bf(v.z - t2 - ((r == c + 2) ? GAMMA : 0.0f));
    o.w = f2bf(v.w - t3 - ((r == c + 3) ? GAMMA : 0.0f));
    *(ushort4*)(Abf + e) = o;
  }
}

// Hr = Zs_r * h  (both bf16; h taken from Xcat's h-half)
__global__ void phase3_kernel(const unsigned short* __restrict__ Zs,
                              const unsigned short* __restrict__ Xcat,
                              unsigned short* __restrict__ hr) {
  const int total4 = BATCH * 1024 / 4;
  for (int i = blockIdx.x * blockDim.x + threadIdx.x; i < total4; i += gridDim.x * blockDim.x) {
    const int e = i * 4;
    const int m = e >> 10;
    const int n = e & 1023;
    ushort4 rs = *(const ushort4*)(Zs + (size_t)m * 2048 + 1024 + n);
    ushort4 hv = *(const ushort4*)(Xcat + (size_t)m * 2048 + 1024 + n);
    ushort4 o;
    o.x = f2bf(bf2f(rs.x) * bf2f(hv.x));
    o.y = f2bf(bf2f(rs.y) * bf2f(hv.y));
    o.z = f2bf(bf2f(rs.z) * bf2f(hv.z));
    o.w = f2bf(bf2f(rs.w) * bf2f(hv.w));
    *(ushort4*)(hr + e) = o;
  }
}

// ---------- launch ----------
extern "C" void kernel_launch(void* const* d_in, const int* in_sizes, int n_in,
                              void* d_out, int out_size, void* d_ws, size_t ws_size,
                              hipStream_t stream) {
  const float* x   = (const float*)d_in[0];
  const float* h   = (const float*)d_in[1];
  const float* Wz  = (const float*)d_in[2];
  const float* bz  = (const float*)d_in[3];
  const float* Uz  = (const float*)d_in[4];
  const float* Wr  = (const float*)d_in[5];
  const float* br  = (const float*)d_in[6];
  const float* Ur  = (const float*)d_in[7];
  const float* Vh  = (const float*)d_in[8];
  const float* bh  = (const float*)d_in[9];
  const float* Wh  = (const float*)d_in[10];
  const float* eps = (const float*)d_in[11];
  float* out = (float*)d_out;

  char* ws = (char*)d_ws;
  size_t off = 0;
  unsigned short* Xcat = (unsigned short*)(ws + off); off += (size_t)BATCH * 2048 * 2;
  unsigned short* Wcat = (unsigned short*)(ws + off); off += (size_t)2048 * 2048 * 2;
  unsigned short* Vhb  = (unsigned short*)(ws + off); off += (size_t)1024 * 1024 * 2;
  unsigned short* Abf  = (unsigned short*)(ws + off); off += (size_t)1024 * 1024 * 2;
  unsigned short* Zs   = (unsigned short*)(ws + off); off += (size_t)BATCH * 2048 * 2;
  unsigned short* Vpre = (unsigned short*)(ws + off); off += (size_t)BATCH * 1024 * 2;
  unsigned short* Hr   = (unsigned short*)(ws + off); off += (size_t)BATCH * 1024 * 2;

  dim3 blk(256);
  prep_x_kernel<<<2048, blk, 0, stream>>>(x, h, Xcat);
  prep_wcat_kernel<<<1024, blk, 0, stream>>>(Wz, Uz, Wr, Ur, Wcat);
  cast_f2b_kernel<<<256, blk, 0, stream>>>(Vh, Vhb, 1024 * 1024 / 4);
  prep_A_kernel<<<256, blk, 0, stream>>>(Wh, Abf);

  dim3 gblk(512);
  // GEMM1: Zs = sigmoid(Xcat @ Wcat^T + [bz|br])   (both gate halves)
  gemm_sig<<<(BATCH / 256) * (2048 / 256), gblk, 0, stream>>>(
      Xcat, Wcat, Zs, 2048, 2048, 2048, bz, br);
  // GEMM2: Vpre = x @ Vh^T   (plain epilogue -- A/B control for gemm_combine)
  gemm_plain<<<(BATCH / 256) * (1024 / 256), gblk, 0, stream>>>(
      Xcat, Vhb, Vpre, 2048, 1024, 1024);
  // Hr = Zs_r * h
  phase3_kernel<<<2048, blk, 0, stream>>>(Zs, Xcat, Hr);
  // GEMM3 fused: out = h + eps*Zs_z*tanh(Vpre + bh + Hr@A^T)
  gemm_combine<<<(BATCH / 256) * (1024 / 256), gblk, 0, stream>>>(
      Hr, Abf, 1024, 1024, 1024, Zs, Vpre, bh, h, eps, out);
}